// Round 12
// baseline (372.814 us; speedup 1.0000x reference)
//
#include <hip/hip_runtime.h>
#include <hip/hip_fp16.h>

#define IN_CH 512
#define HEADS 8
#define NEG_SLOPE 0.2f

// ---- direct 256-node bucket geometry (shared by binning + aggregation) ----
#define RB 256               // nodes per bucket
#define RB_BITS 8
#define NB_MAX 400           // >= ceil(100000/256)=391
#define LCAP 8               // per-block per-bucket LDS staging (lambda=5.24, ~5% overflow)
#define BCAP 9216            // per-bucket capacity (mean 8184, +11 sigma)
#define GT_STRIDE 16         // tail counters 64B apart (one cache line each)
#define EPT 9                // k_agg edges per thread: 9*1024 = 9216 covers BCAP

typedef _Float16 f16x8 __attribute__((ext_vector_type(8)));
typedef float f32x4 __attribute__((ext_vector_type(4)));

union F16x8 {
    f16x8 v;
    __half2 h2[4];
    float4 f4;
};

__device__ __forceinline__ float lrelu(float v) {
    return v > 0.f ? v : NEG_SLOPE * v;
}

// ---- fused: blocks [0,GB) MFMA gemm ; rest = LDS-binned scatter ----
// GEMM via mfma_f32_16x16x32_f16: one wave = 16 rows; per tile 16 MFMA +
// 32 loads + cvt, replacing the old 16x(64 FMA + 96 shfl) issue stream
// (round-9/10 diagnosis: DS-pipe reduce was 3x the math). W fragments
// prepacked to fp16 in LDS (16 steps x 64 lanes x 16B = 16KB); A converted
// f32->fp16 RNE in flight. C/D layout: col=lane&15, row=(lane>>4)*4+reg
// (HW-verified m89). A/B share the same (group,slot)->k convention, so the
// contraction is correct for any k-bijection.
__global__ __launch_bounds__(256)
void k_fused(const float* __restrict__ x, const float* __restrict__ W,
             __half* __restrict__ h, const int* __restrict__ ei,
             int* __restrict__ gtail, int* __restrict__ bucket,
             int n, int E, int gemmBlocks, int nb) {
    __shared__ __align__(16) char smem[16384];   // union: bfrag | scatter bins

    if ((int)blockIdx.x < gemmBlocks) {
        float4* bfrag = (float4*)smem;
        // prepack W -> fp16 B-fragments: slot t = (step s, lane l)
        for (int t = threadIdx.x; t < 1024; t += 256) {
            int s = t >> 6;
            int l = t & 63;
            int g = l >> 4;
            int col = l & 7;       // cols 8..15 duplicate 0..7 (C cols >=8 unused)
            F16x8 u;
#pragma unroll
            for (int j = 0; j < 4; ++j) {
                float w0 = W[(s * 32 + g * 8 + 2 * j) * 8 + col];
                float w1 = W[(s * 32 + g * 8 + 2 * j + 1) * 8 + col];
                u.h2[j] = __floats2half2_rn(w0, w1);
            }
            bfrag[t] = u.f4;
        }
        __syncthreads();

        const int lane = threadIdx.x & 63;
        const int wave = (int)((blockIdx.x * 256 + threadIdx.x) >> 6);
        const int nwav = gemmBlocks * 4;
        const int r = lane & 15;
        const int g = lane >> 4;
        const int ntiles = n >> 4;           // 100000/16 = 6250 exactly
        for (int tile = wave; tile < ntiles; tile += nwav) {
            const int row16 = tile << 4;
            const float* xp = x + (size_t)(row16 + r) * IN_CH + g * 8;
            f32x4 acc = {0.f, 0.f, 0.f, 0.f};
#pragma unroll
            for (int s = 0; s < 16; ++s) {
                float4 xa = *(const float4*)(xp + s * 32);
                float4 xb = *(const float4*)(xp + s * 32 + 4);
                F16x8 a;
                a.h2[0] = __floats2half2_rn(xa.x, xa.y);
                a.h2[1] = __floats2half2_rn(xa.z, xa.w);
                a.h2[2] = __floats2half2_rn(xb.x, xb.y);
                a.h2[3] = __floats2half2_rn(xb.z, xb.w);
                F16x8 b;
                b.f4 = bfrag[s * 64 + lane];
                acc = __builtin_amdgcn_mfma_f32_16x16x32_f16(a.v, b.v, acc, 0, 0, 0);
            }
            const int c = lane & 15;
            if (c < 8) {
                const int rb = row16 + (lane >> 4) * 4;
#pragma unroll
                for (int reg = 0; reg < 4; ++reg)
                    h[(size_t)(rb + reg) * 8 + c] = __float2half(acc[reg]);
            }
        }
        return;
    }

    // ---- scatter path (round-7-proven LDS-binned form) ----
    int* lcnt = (int*)smem;              // NB_MAX
    int* gbase = lcnt + NB_MAX;          // NB_MAX
    int* lst = gbase + NB_MAX;           // NB_MAX*LCAP  (total 16000B <= 16384)

    for (int i = threadIdx.x; i < nb; i += 256) lcnt[i] = 0;
    __syncthreads();

    int sb = blockIdx.x - gemmBlocks;
    int base = sb * 2048 + (int)threadIdx.x * 8;
    if (base < E) {
        if (base + 8 <= E) {
            int4 s0 = *(const int4*)(ei + base);
            int4 s1 = *(const int4*)(ei + base + 4);
            int4 d0 = *(const int4*)(ei + E + base);
            int4 d1 = *(const int4*)(ei + E + base + 4);
            int ss[8] = {s0.x, s0.y, s0.z, s0.w, s1.x, s1.y, s1.z, s1.w};
            int dd[8] = {d0.x, d0.y, d0.z, d0.w, d1.x, d1.y, d1.z, d1.w};
#pragma unroll
            for (int k = 0; k < 8; ++k) {
                int b = dd[k] >> RB_BITS;
                int v = (ss[k] << RB_BITS) | (dd[k] & (RB - 1));
                int p = atomicAdd(&lcnt[b], 1);
                if (p < LCAP) {
                    lst[b * LCAP + p] = v;
                } else {                       // ~5% of edges: direct (padded line)
                    int g2 = atomicAdd(gtail + (b << 4), 1);
                    if (g2 < BCAP) bucket[(size_t)b * BCAP + g2] = v;
                }
            }
        } else {
            for (int k = 0; base + k < E; ++k) {
                int s = ei[base + k];
                int d = ei[E + base + k];
                int b = d >> RB_BITS;
                int v = (s << RB_BITS) | (d & (RB - 1));
                int p = atomicAdd(&lcnt[b], 1);
                if (p < LCAP) {
                    lst[b * LCAP + p] = v;
                } else {
                    int g2 = atomicAdd(gtail + (b << 4), 1);
                    if (g2 < BCAP) bucket[(size_t)b * BCAP + g2] = v;
                }
            }
        }
    }
    __syncthreads();

    for (int b = threadIdx.x; b < nb; b += 256) {
        int c = min(lcnt[b], LCAP);
        gbase[b] = c ? atomicAdd(gtail + (b << 4), c) : 0;
    }
    __syncthreads();

    int tot = nb * LCAP;
    for (int pr = threadIdx.x; pr < tot; pr += 256) {
        int b = pr >> 3;
        int i = pr & (LCAP - 1);
        if (i < min(lcnt[b], LCAP)) {
            int pos = gbase[b] + i;
            if (pos < BCAP) bucket[(size_t)b * BCAP + pos] = lst[b * LCAP + i];
        }
    }
}

// ---- per-bucket: counting sort + atomic-free aggregation (round-11 form) ----
__global__ __launch_bounds__(1024, 4)
void k_agg(const __half* __restrict__ h, const int* __restrict__ bucket,
           const int* __restrict__ gtail,
           const float* __restrict__ att_src, const float* __restrict__ att_dst,
           const float* __restrict__ gat_bias, const float* __restrict__ lin_w,
           const float* __restrict__ lin_b, const float* __restrict__ bias,
           float* __restrict__ out, int n) {
    __shared__ int elds[BCAP];           // sorted src ids        (36 KB)
    __shared__ float hw[HEADS][RB];      // dst-window h (f32)     (8 KB)
    __shared__ int cnt[RB];
    __shared__ int scn[RB];
    __shared__ int pcnt[RB];

    const int b = blockIdx.x;
    const int base = b << RB_BITS;
    const int Wn = min(RB, n - base);
    const int tid = threadIdx.x;

    for (int i = tid; i < RB; i += 1024) { cnt[i] = 0; pcnt[i] = 0; }
    for (int i = tid; i < Wn * 8; i += 1024)
        hw[i & 7][i >> 3] = __half2float(h[(size_t)(base + (i >> 3)) * 8 + (i & 7)]);

    const int tail = min(gtail[b << 4], BCAP);
    const int* __restrict__ lstp = bucket + (size_t)b * BCAP;

    // pass A: 9 independent coalesced loads, cached in registers
    int vv[EPT];
#pragma unroll
    for (int r = 0; r < EPT; ++r) {
        int idx = tid + r * 1024;
        vv[r] = (idx < tail) ? lstp[idx] : -1;
    }
    __syncthreads();
#pragma unroll
    for (int r = 0; r < EPT; ++r)
        if (vv[r] >= 0) atomicAdd(&cnt[vv[r] & (RB - 1)], 1);
    __syncthreads();

    // inclusive scan cnt -> scn
    if (tid < RB) scn[tid] = cnt[tid];
    __syncthreads();
    for (int off = 1; off < RB; off <<= 1) {
        int v = 0;
        if (tid < RB) {
            v = scn[tid];
            if (tid >= off) v += scn[tid - off];
        }
        __syncthreads();
        if (tid < RB) scn[tid] = v;
        __syncthreads();
    }

    // pass B: place src ids from registers, grouped by dst node
#pragma unroll
    for (int r = 0; r < EPT; ++r) {
        if (vv[r] >= 0) {
            int ln = vv[r] & (RB - 1);
            int pos = scn[ln] - cnt[ln] + atomicAdd(&pcnt[ln], 1);
            if (pos < BCAP) elds[pos] = vv[r] >> RB_BITS;
        }
    }
    __syncthreads();

    float as[8], ad[8];
#pragma unroll
    for (int q = 0; q < 8; ++q) { as[q] = att_src[q]; ad[q] = att_dst[q]; }

    // aggregation: quad of lanes per node, 4 gathers (16B each) in flight
    const int ln = tid >> 2;
    const int j = tid & 3;
    float num[8] = {0.f, 0.f, 0.f, 0.f, 0.f, 0.f, 0.f, 0.f};
    float den[8] = {0.f, 0.f, 0.f, 0.f, 0.f, 0.f, 0.f, 0.f};
    if (ln < Wn) {
        float hadd[8];                       // loop-invariant hoist
#pragma unroll
        for (int q = 0; q < 8; ++q) hadd[q] = hw[q][ln] * ad[q];
        const int deg = cnt[ln];
        const int st = scn[ln] - deg;
        int i = j;
        for (; i + 12 < deg; i += 16) {      // 4 edges in flight
            int sv[4] = {elds[st + i], elds[st + i + 4],
                         elds[st + i + 8], elds[st + i + 12]};
            float4 raw[4];
#pragma unroll
            for (int k = 0; k < 4; ++k)
                raw[k] = *(const float4*)(h + (size_t)sv[k] * 8);
#pragma unroll
            for (int k = 0; k < 4; ++k) {
                const __half2* q2 = (const __half2*)&raw[k];
                float2 f01 = __half22float2(q2[0]);
                float2 f23 = __half22float2(q2[1]);
                float2 f45 = __half22float2(q2[2]);
                float2 f67 = __half22float2(q2[3]);
                float hs[8] = {f01.x, f01.y, f23.x, f23.y,
                               f45.x, f45.y, f67.x, f67.y};
#pragma unroll
                for (int q = 0; q < 8; ++q) {
                    float e = lrelu(fmaf(hs[q], as[q], hadd[q]));
                    float p = __expf(e);
                    den[q] += p;
                    num[q] = fmaf(p, hs[q], num[q]);
                }
            }
        }
        for (; i < deg; i += 4) {
            int s = elds[st + i];
            float4 raw = *(const float4*)(h + (size_t)s * 8);
            const __half2* q2 = (const __half2*)&raw;
            float2 f01 = __half22float2(q2[0]);
            float2 f23 = __half22float2(q2[1]);
            float2 f45 = __half22float2(q2[2]);
            float2 f67 = __half22float2(q2[3]);
            float hs[8] = {f01.x, f01.y, f23.x, f23.y,
                           f45.x, f45.y, f67.x, f67.y};
#pragma unroll
            for (int q = 0; q < 8; ++q) {
                float e = lrelu(fmaf(hs[q], as[q], hadd[q]));
                float p = __expf(e);
                den[q] += p;
                num[q] = fmaf(p, hs[q], num[q]);
            }
        }
    }
#pragma unroll
    for (int q = 0; q < 8; ++q) {
        num[q] += __shfl_xor(num[q], 1, 64);
        num[q] += __shfl_xor(num[q], 2, 64);
        den[q] += __shfl_xor(den[q], 1, 64);
        den[q] += __shfl_xor(den[q], 2, 64);
    }

    if (ln < Wn && j == 0) {
        float t = 0.f;
        float lb = lin_b[0], bs = bias[0];
#pragma unroll
        for (int q = 0; q < 8; ++q) {
            float hv = hw[q][ln];
            float e = lrelu(hv * (as[q] + ad[q]));   // self-loop score
            float p = __expf(e);
            float nm = fmaf(p, hv, num[q]);
            float dn = den[q] + p;
            float o = nm / (dn + 1e-16f) + gat_bias[q];
            t = fmaf(o, lin_w[q], t);
        }
        out[base + ln] = fmaxf(t + lb, 0.f) + bs;
    }
}

extern "C" void kernel_launch(void* const* d_in, const int* in_sizes, int n_in,
                              void* d_out, int out_size, void* d_ws, size_t ws_size,
                              hipStream_t stream) {
    const float* x = (const float*)d_in[0];
    const int* ei = (const int*)d_in[1];
    const float* W = (const float*)d_in[2];
    const float* att_src = (const float*)d_in[3];
    const float* att_dst = (const float*)d_in[4];
    const float* gat_bias = (const float*)d_in[5];
    const float* lin_w = (const float*)d_in[6];
    const float* lin_b = (const float*)d_in[7];
    const float* bias = (const float*)d_in[8];

    const int n = in_sizes[0] / IN_CH;       // 100000
    const int E = in_sizes[1] / 2;           // 3.2M
    const int nb = (n + RB - 1) >> RB_BITS;  // 391 buckets

    // workspace: h [n*8 fp16 = 1.6MB] | gtail [nb*16 i32, 64B-padded] | bucket
    __half* h = (__half*)d_ws;
    int* gtail = (int*)(h + (size_t)n * HEADS);
    int* bucket = gtail + (size_t)nb * GT_STRIDE;

    hipMemsetAsync(gtail, 0, (size_t)nb * GT_STRIDE * sizeof(int), stream);

    const int GB = 512;                      // 2048 MFMA waves, ~3 tiles each
    const int SB = (E + 2047) / 2048;
    k_fused<<<GB + SB, 256, 0, stream>>>(x, W, h, ei, gtail, bucket, n, E, GB, nb);
    k_agg<<<nb, 1024, 0, stream>>>(h, bucket, gtail, att_src, att_dst,
                                   gat_bias, lin_w, lin_b, bias,
                                   (float*)d_out, n);
}

// Round 13
// 357.849 us; speedup vs baseline: 1.0418x; 1.0418x over previous
//
#include <hip/hip_runtime.h>
#include <hip/hip_fp16.h>

#define IN_CH 512
#define HEADS 8
#define NEG_SLOPE 0.2f

// ---- direct 256-node bucket geometry (shared by binning + aggregation) ----
#define RB 256               // nodes per bucket
#define RB_BITS 8
#define NB_MAX 400           // >= ceil(100000/256)=391
#define LCAP 32              // per-block per-bucket staging (lambda=20.9, ~1% overflow)
#define BCAP 9216            // per-bucket capacity (mean 8184, +11 sigma)
#define GT_STRIDE 16         // tail counters 64B apart
#define EPT 9                // k_agg edges per thread: 9*1024 = 9216 covers BCAP
#define SMEM_BYTES 54400     // max(gemm 16KB, scatter lcnt+gbase+lst)

typedef _Float16 f16x8 __attribute__((ext_vector_type(8)));
typedef float f32x4 __attribute__((ext_vector_type(4)));

union F16x8 {
    f16x8 v;
    __half2 h2[4];
    float4 f4;
};

__device__ __forceinline__ float lrelu(float v) {
    return v > 0.f ? v : NEG_SLOPE * v;
}

// ---- fused: blocks [0,GB) MFMA gemm ; rest = 8192-edge binned scatter ----
// Round-12 null: MFMA gemm left k_fused at 119us (nothing busy) => the wall
// is same-ADDRESS atomic serialization on gtail (calib: round-4 direct
// scatter = 8184 RMW/addr = 207us => ~25ns/RMW; binned 1970/addr ~ 50-118us).
// This round: 8192-edge scatter blocks => 391 blocks => 391 RMW/addr (5x cut).
__global__ __launch_bounds__(256)
void k_fused(const float* __restrict__ x, const float* __restrict__ W,
             __half* __restrict__ h, const int* __restrict__ ei,
             int* __restrict__ gtail, int* __restrict__ bucket,
             int n, int E, int gemmBlocks, int nb) {
    __shared__ __align__(16) char smem[SMEM_BYTES];

    if ((int)blockIdx.x < gemmBlocks) {
        float4* bfrag = (float4*)smem;
        // prepack W -> fp16 B-fragments: slot t = (step s, lane l)
        for (int t = threadIdx.x; t < 1024; t += 256) {
            int s = t >> 6;
            int l = t & 63;
            int g = l >> 4;
            int col = l & 7;       // cols 8..15 duplicate 0..7 (C cols >=8 unused)
            F16x8 u;
#pragma unroll
            for (int j = 0; j < 4; ++j) {
                float w0 = W[(s * 32 + g * 8 + 2 * j) * 8 + col];
                float w1 = W[(s * 32 + g * 8 + 2 * j + 1) * 8 + col];
                u.h2[j] = __floats2half2_rn(w0, w1);
            }
            bfrag[t] = u.f4;
        }
        __syncthreads();

        const int lane = threadIdx.x & 63;
        const int wave = (int)((blockIdx.x * 256 + threadIdx.x) >> 6);
        const int nwav = gemmBlocks * 4;
        const int r = lane & 15;
        const int g = lane >> 4;
        const int ntiles = n >> 4;           // 100000/16 = 6250 exactly
        for (int tile = wave; tile < ntiles; tile += nwav) {
            const int row16 = tile << 4;
            const float* xp = x + (size_t)(row16 + r) * IN_CH + g * 8;
            f32x4 acc = {0.f, 0.f, 0.f, 0.f};
#pragma unroll
            for (int s = 0; s < 16; ++s) {
                float4 xa = *(const float4*)(xp + s * 32);
                float4 xb = *(const float4*)(xp + s * 32 + 4);
                F16x8 a;
                a.h2[0] = __floats2half2_rn(xa.x, xa.y);
                a.h2[1] = __floats2half2_rn(xa.z, xa.w);
                a.h2[2] = __floats2half2_rn(xb.x, xb.y);
                a.h2[3] = __floats2half2_rn(xb.z, xb.w);
                F16x8 b;
                b.f4 = bfrag[s * 64 + lane];
                acc = __builtin_amdgcn_mfma_f32_16x16x32_f16(a.v, b.v, acc, 0, 0, 0);
            }
            const int c = lane & 15;
            if (c < 8) {
                const int rb = row16 + (lane >> 4) * 4;
#pragma unroll
                for (int reg = 0; reg < 4; ++reg)
                    h[(size_t)(rb + reg) * 8 + c] = __float2half(acc[reg]);
            }
        }
        return;
    }

    // ---- scatter path: 8192 edges/block (4 rounds of the proven 2048 body) --
    int* lcnt = (int*)smem;              // [NB_MAX]
    int* gbase = lcnt + NB_MAX;          // [NB_MAX]
    int* lst = gbase + NB_MAX;           // [NB_MAX * LCAP]

    for (int i = threadIdx.x; i < nb; i += 256) lcnt[i] = 0;
    __syncthreads();

    int sb = blockIdx.x - gemmBlocks;
    for (int rnd = 0; rnd < 4; ++rnd) {
        int base = sb * 8192 + rnd * 2048 + (int)threadIdx.x * 8;
        if (base >= E) continue;
        if (base + 8 <= E) {
            int4 s0 = *(const int4*)(ei + base);
            int4 s1 = *(const int4*)(ei + base + 4);
            int4 d0 = *(const int4*)(ei + E + base);
            int4 d1 = *(const int4*)(ei + E + base + 4);
            int ss[8] = {s0.x, s0.y, s0.z, s0.w, s1.x, s1.y, s1.z, s1.w};
            int dd[8] = {d0.x, d0.y, d0.z, d0.w, d1.x, d1.y, d1.z, d1.w};
#pragma unroll
            for (int k = 0; k < 8; ++k) {
                int b = dd[k] >> RB_BITS;
                int v = (ss[k] << RB_BITS) | (dd[k] & (RB - 1));
                int p = atomicAdd(&lcnt[b], 1);
                if (p < LCAP) {
                    lst[b * LCAP + p] = v;
                } else {                       // ~1% of edges: direct (padded line)
                    int g2 = atomicAdd(gtail + (b << 4), 1);
                    if (g2 < BCAP) bucket[(size_t)b * BCAP + g2] = v;
                }
            }
        } else {
            for (int k = 0; base + k < E; ++k) {
                int s = ei[base + k];
                int d = ei[E + base + k];
                int b = d >> RB_BITS;
                int v = (s << RB_BITS) | (d & (RB - 1));
                int p = atomicAdd(&lcnt[b], 1);
                if (p < LCAP) {
                    lst[b * LCAP + p] = v;
                } else {
                    int g2 = atomicAdd(gtail + (b << 4), 1);
                    if (g2 < BCAP) bucket[(size_t)b * BCAP + g2] = v;
                }
            }
        }
    }
    __syncthreads();

    // reserve: ONE tail atomic per (block,bucket) => 391 RMW per address total
    for (int b = threadIdx.x; b < nb; b += 256) {
        int c = min(lcnt[b], LCAP);
        gbase[b] = c ? atomicAdd(gtail + (b << 4), c) : 0;
    }
    __syncthreads();

    // flush: 32 consecutive lanes per bucket -> 128B coalesced stores
    int tot = nb * LCAP;
    for (int pr = threadIdx.x; pr < tot; pr += 256) {
        int b = pr >> 5;
        int i = pr & (LCAP - 1);
        if (i < min(lcnt[b], LCAP)) {
            int pos = gbase[b] + i;
            if (pos < BCAP) bucket[(size_t)b * BCAP + pos] = lst[b * LCAP + i];
        }
    }
}

// ---- per-bucket: counting sort + atomic-free aggregation (round-11 form) ----
__global__ __launch_bounds__(1024, 4)
void k_agg(const __half* __restrict__ h, const int* __restrict__ bucket,
           const int* __restrict__ gtail,
           const float* __restrict__ att_src, const float* __restrict__ att_dst,
           const float* __restrict__ gat_bias, const float* __restrict__ lin_w,
           const float* __restrict__ lin_b, const float* __restrict__ bias,
           float* __restrict__ out, int n) {
    __shared__ int elds[BCAP];           // sorted src ids        (36 KB)
    __shared__ float hw[HEADS][RB];      // dst-window h (f32)     (8 KB)
    __shared__ int cnt[RB];
    __shared__ int scn[RB];
    __shared__ int pcnt[RB];

    const int b = blockIdx.x;
    const int base = b << RB_BITS;
    const int Wn = min(RB, n - base);
    const int tid = threadIdx.x;

    for (int i = tid; i < RB; i += 1024) { cnt[i] = 0; pcnt[i] = 0; }
    for (int i = tid; i < Wn * 8; i += 1024)
        hw[i & 7][i >> 3] = __half2float(h[(size_t)(base + (i >> 3)) * 8 + (i & 7)]);

    const int tail = min(gtail[b << 4], BCAP);
    const int* __restrict__ lstp = bucket + (size_t)b * BCAP;

    // pass A: 9 independent coalesced loads, cached in registers
    int vv[EPT];
#pragma unroll
    for (int r = 0; r < EPT; ++r) {
        int idx = tid + r * 1024;
        vv[r] = (idx < tail) ? lstp[idx] : -1;
    }
    __syncthreads();
#pragma unroll
    for (int r = 0; r < EPT; ++r)
        if (vv[r] >= 0) atomicAdd(&cnt[vv[r] & (RB - 1)], 1);
    __syncthreads();

    // inclusive scan cnt -> scn
    if (tid < RB) scn[tid] = cnt[tid];
    __syncthreads();
    for (int off = 1; off < RB; off <<= 1) {
        int v = 0;
        if (tid < RB) {
            v = scn[tid];
            if (tid >= off) v += scn[tid - off];
        }
        __syncthreads();
        if (tid < RB) scn[tid] = v;
        __syncthreads();
    }

    // pass B: place src ids from registers, grouped by dst node
#pragma unroll
    for (int r = 0; r < EPT; ++r) {
        if (vv[r] >= 0) {
            int ln = vv[r] & (RB - 1);
            int pos = scn[ln] - cnt[ln] + atomicAdd(&pcnt[ln], 1);
            if (pos < BCAP) elds[pos] = vv[r] >> RB_BITS;
        }
    }
    __syncthreads();

    float as[8], ad[8];
#pragma unroll
    for (int q = 0; q < 8; ++q) { as[q] = att_src[q]; ad[q] = att_dst[q]; }

    // aggregation: quad of lanes per node, 4 gathers (16B each) in flight
    const int ln = tid >> 2;
    const int j = tid & 3;
    float num[8] = {0.f, 0.f, 0.f, 0.f, 0.f, 0.f, 0.f, 0.f};
    float den[8] = {0.f, 0.f, 0.f, 0.f, 0.f, 0.f, 0.f, 0.f};
    if (ln < Wn) {
        float hadd[8];                       // loop-invariant hoist
#pragma unroll
        for (int q = 0; q < 8; ++q) hadd[q] = hw[q][ln] * ad[q];
        const int deg = cnt[ln];
        const int st = scn[ln] - deg;
        int i = j;
        for (; i + 12 < deg; i += 16) {      // 4 edges in flight
            int sv[4] = {elds[st + i], elds[st + i + 4],
                         elds[st + i + 8], elds[st + i + 12]};
            float4 raw[4];
#pragma unroll
            for (int k = 0; k < 4; ++k)
                raw[k] = *(const float4*)(h + (size_t)sv[k] * 8);
#pragma unroll
            for (int k = 0; k < 4; ++k) {
                const __half2* q2 = (const __half2*)&raw[k];
                float2 f01 = __half22float2(q2[0]);
                float2 f23 = __half22float2(q2[1]);
                float2 f45 = __half22float2(q2[2]);
                float2 f67 = __half22float2(q2[3]);
                float hs[8] = {f01.x, f01.y, f23.x, f23.y,
                               f45.x, f45.y, f67.x, f67.y};
#pragma unroll
                for (int q = 0; q < 8; ++q) {
                    float e = lrelu(fmaf(hs[q], as[q], hadd[q]));
                    float p = __expf(e);
                    den[q] += p;
                    num[q] = fmaf(p, hs[q], num[q]);
                }
            }
        }
        for (; i < deg; i += 4) {
            int s = elds[st + i];
            float4 raw = *(const float4*)(h + (size_t)s * 8);
            const __half2* q2 = (const __half2*)&raw;
            float2 f01 = __half22float2(q2[0]);
            float2 f23 = __half22float2(q2[1]);
            float2 f45 = __half22float2(q2[2]);
            float2 f67 = __half22float2(q2[3]);
            float hs[8] = {f01.x, f01.y, f23.x, f23.y,
                           f45.x, f45.y, f67.x, f67.y};
#pragma unroll
            for (int q = 0; q < 8; ++q) {
                float e = lrelu(fmaf(hs[q], as[q], hadd[q]));
                float p = __expf(e);
                den[q] += p;
                num[q] = fmaf(p, hs[q], num[q]);
            }
        }
    }
#pragma unroll
    for (int q = 0; q < 8; ++q) {
        num[q] += __shfl_xor(num[q], 1, 64);
        num[q] += __shfl_xor(num[q], 2, 64);
        den[q] += __shfl_xor(den[q], 1, 64);
        den[q] += __shfl_xor(den[q], 2, 64);
    }

    if (ln < Wn && j == 0) {
        float t = 0.f;
        float lb = lin_b[0], bs = bias[0];
#pragma unroll
        for (int q = 0; q < 8; ++q) {
            float hv = hw[q][ln];
            float e = lrelu(hv * (as[q] + ad[q]));   // self-loop score
            float p = __expf(e);
            float nm = fmaf(p, hv, num[q]);
            float dn = den[q] + p;
            float o = nm / (dn + 1e-16f) + gat_bias[q];
            t = fmaf(o, lin_w[q], t);
        }
        out[base + ln] = fmaxf(t + lb, 0.f) + bs;
    }
}

extern "C" void kernel_launch(void* const* d_in, const int* in_sizes, int n_in,
                              void* d_out, int out_size, void* d_ws, size_t ws_size,
                              hipStream_t stream) {
    const float* x = (const float*)d_in[0];
    const int* ei = (const int*)d_in[1];
    const float* W = (const float*)d_in[2];
    const float* att_src = (const float*)d_in[3];
    const float* att_dst = (const float*)d_in[4];
    const float* gat_bias = (const float*)d_in[5];
    const float* lin_w = (const float*)d_in[6];
    const float* lin_b = (const float*)d_in[7];
    const float* bias = (const float*)d_in[8];

    const int n = in_sizes[0] / IN_CH;       // 100000
    const int E = in_sizes[1] / 2;           // 3.2M
    const int nb = (n + RB - 1) >> RB_BITS;  // 391 buckets

    // workspace: h [n*8 fp16 = 1.6MB] | gtail [nb*16 i32, 64B-padded] | bucket
    __half* h = (__half*)d_ws;
    int* gtail = (int*)(h + (size_t)n * HEADS);
    int* bucket = gtail + (size_t)nb * GT_STRIDE;

    hipMemsetAsync(gtail, 0, (size_t)nb * GT_STRIDE * sizeof(int), stream);

    const int GB = 1024;                     // MFMA gemm waves
    const int SB = (E + 8191) / 8192;        // 391 scatter blocks (8192 edges each)
    k_fused<<<GB + SB, 256, 0, stream>>>(x, W, h, ei, gtail, bucket, n, E, GB, nb);
    k_agg<<<nb, 1024, 0, stream>>>(h, bucket, gtail, att_src, att_dst,
                                   gat_bias, lin_w, lin_b, bias,
                                   (float*)d_out, n);
}